// Round 7
// baseline (276.797 us; speedup 1.0000x reference)
//
#include <hip/hip_runtime.h>
#include <hip/hip_bf16.h>
#include <math.h>

// Problem constants (match reference)
#define SS 2048
#define BB 4
#define DD 256
#define EE 256
#define HH 8
#define HD 32
#define TT (SS*BB)   // 8192 tokens

#define NBLK 256     // one block per CU -> co-resident
#define NTHR 512     // 8 waves

typedef unsigned short ushortt;
typedef __attribute__((ext_vector_type(8))) short short8;
typedef __attribute__((ext_vector_type(4))) float f32x4;

__device__ __forceinline__ float bfbits2f(ushortt u) {
    return __uint_as_float(((unsigned int)u) << 16);
}
__device__ __forceinline__ ushortt f2bf_bits(float f) {
    unsigned int u = __float_as_uint(f);
    unsigned int r = u + 0x7FFFu + ((u >> 16) & 1u);  // RNE
    return (ushortt)(r >> 16);
}

__device__ __forceinline__ int robust_req(const void* p) {
    int i = *(const int*)p;
    if (i >= 1 && i <= SS) return i;
    float f = __int_as_float(i);
    if (f >= 1.f && f <= (float)SS) return (int)(f + 0.5f);
    float b = bfbits2f(*(const ushortt*)p);
    if (b >= 1.f && b <= (float)SS) return (int)(b + 0.5f);
    return 16;
}

// Generational grid barrier (device scope). cnt/gen zeroed by memset each launch.
__device__ __forceinline__ void grid_sync(unsigned* cnt, unsigned* gen) {
    __syncthreads();
    if (threadIdx.x == 0) {
        __threadfence();
        unsigned g = __hip_atomic_load(gen, __ATOMIC_RELAXED, __HIP_MEMORY_SCOPE_AGENT);
        unsigned a = __hip_atomic_fetch_add(cnt, 1u, __ATOMIC_ACQ_REL, __HIP_MEMORY_SCOPE_AGENT);
        if (a + 1 == (unsigned)NBLK) {
            __hip_atomic_store(cnt, 0u, __ATOMIC_RELAXED, __HIP_MEMORY_SCOPE_AGENT);
            __hip_atomic_store(gen, g + 1u, __ATOMIC_RELEASE, __HIP_MEMORY_SCOPE_AGENT);
        } else {
            long long spins = 0;
            while (__hip_atomic_load(gen, __ATOMIC_ACQUIRE, __HIP_MEMORY_SCOPE_AGENT) == g) {
                __builtin_amdgcn_s_sleep(2);
                if (++spins > (1LL << 22)) break;   // bail out instead of hanging
            }
        }
        __threadfence();
    }
    __syncthreads();
}

__global__ __launch_bounds__(NTHR, 1)
void mega(const float* __restrict__ mod,
          const float* __restrict__ Win,
          const float* __restrict__ Wq, const float* __restrict__ Wk,
          const float* __restrict__ Wv,
          const float* __restrict__ bq, const float* __restrict__ bk,
          const float* __restrict__ bv, const float* __restrict__ bin_,
          const float* __restrict__ Wfc, const float* __restrict__ Wout,
          const float* __restrict__ bout, const float* __restrict__ bfc,
          const float* __restrict__ gamma, const float* __restrict__ beta,
          const void* __restrict__ reqp,
          float* __restrict__ beff, float* __restrict__ b2,
          ushortt* __restrict__ Weffb, ushortt* __restrict__ W2b,
          ushortt* __restrict__ qkvb, ushortt* __restrict__ ctxb,
          float* __restrict__ out,
          unsigned* __restrict__ bar_cnt, unsigned* __restrict__ bar_gen) {
    __shared__ __align__(16) unsigned char smem[24576];

    const int t    = threadIdx.x;
    const int bid  = blockIdx.x;
    const int w    = t >> 6;          // wave 0..7
    const int lane = t & 63;
    const int quad = lane >> 4;
    const int l16  = lane & 15;

    // ---------------- Phase 0: weight folding (1024 virtual blocks, 2 rounds) ---
    {
        float* red = (float*)smem;    // 8 slots
        const int half = t >> 8;      // 0/1
        const int t256 = t & 255;
#pragma unroll 1
        for (int rnd = 0; rnd < 2; ++rnd) {
            int vb = bid * 2 + half + rnd * 512;   // 0..1023
            float tb;
            if (vb < 3 * EE) {
                int r = vb;
                int i = r / EE;
                const float* Wi = (i == 0) ? Wq : ((i == 1) ? Wk : Wv);
                const float* bi = (i == 0) ? bq : ((i == 1) ? bk : bv);
                float acc = 0.f;
                for (int e1 = 0; e1 < EE; ++e1) acc += Win[r * EE + e1] * Wi[e1 * DD + t256];
                Weffb[(size_t)r * DD + t256] = f2bf_bits(acc);
                tb = Win[r * EE + t256] * bi[t256];
            } else {
                int d = vb - 3 * EE;
                float acc = 0.f;
                for (int e = 0; e < EE; ++e) acc += Wfc[d * EE + e] * Wout[e * EE + t256];
                W2b[(size_t)d * EE + t256] = f2bf_bits(acc);
                tb = Wfc[d * EE + t256] * bout[t256];
            }
#pragma unroll
            for (int off = 32; off >= 1; off >>= 1) tb += __shfl_xor(tb, off);
            if (lane == 0) red[w] = tb;
            __syncthreads();
            if (t256 == 0) {
                float s = red[half * 4] + red[half * 4 + 1] + red[half * 4 + 2] + red[half * 4 + 3];
                if (vb < 3 * EE) beff[vb] = s + bin_[vb];
                else             b2[vb - 3 * EE] = s + bfc[vb - 3 * EE];
            }
            __syncthreads();
        }
    }
    grid_sync(bar_cnt, bar_gen);

    // ---------------- Phase 1: qkv GEMM (768 tiles of 128x64, 3/block) ----------
    {
        ushortt (*Alds)[40] = (ushortt (*)[40])smem;              // 128 x 40
        ushortt (*Blds)[40] = (ushortt (*)[40])(smem + 10240);    // 64 x 40
        const int wm = w >> 1, wn = w & 1;
        const int sr = t >> 2;          // 0..127
        const int sp = (t & 3) * 8;
#pragma unroll 1
        for (int i = 0; i < 3; ++i) {
            int tile = bid + 256 * i;            // 0..767
            int m0 = (tile / 12) * 128;
            int n0 = (tile % 12) * 64;
            f32x4 acc[2][2];
#pragma unroll
            for (int fm = 0; fm < 2; ++fm)
#pragma unroll
                for (int fn = 0; fn < 2; ++fn) acc[fm][fn] = (f32x4){0.f,0.f,0.f,0.f};
            for (int k0 = 0; k0 < DD; k0 += 32) {
                const float* ap = mod + (size_t)(m0 + sr) * DD + k0 + sp;
                float4 v0 = *(const float4*)ap;
                float4 v1 = *(const float4*)(ap + 4);
                ushort4 o0, o1;
                o0.x = f2bf_bits(v0.x); o0.y = f2bf_bits(v0.y);
                o0.z = f2bf_bits(v0.z); o0.w = f2bf_bits(v0.w);
                o1.x = f2bf_bits(v1.x); o1.y = f2bf_bits(v1.y);
                o1.z = f2bf_bits(v1.z); o1.w = f2bf_bits(v1.w);
                *(ushort4*)&Alds[sr][sp]     = o0;
                *(ushort4*)&Alds[sr][sp + 4] = o1;
                if (t < 256) {
                    int br = t >> 2;
                    int bp = (t & 3) * 8;
                    *(float4*)&Blds[br][bp] =
                        *(const float4*)(Weffb + (size_t)(n0 + br) * DD + k0 + bp);
                }
                __syncthreads();
                short8 af[2], bfr[2];
#pragma unroll
                for (int fm = 0; fm < 2; ++fm)
                    af[fm] = *(const short8*)&Alds[wm * 32 + fm * 16 + l16][quad * 8];
#pragma unroll
                for (int fn = 0; fn < 2; ++fn)
                    bfr[fn] = *(const short8*)&Blds[wn * 32 + fn * 16 + l16][quad * 8];
#pragma unroll
                for (int fm = 0; fm < 2; ++fm)
#pragma unroll
                    for (int fn = 0; fn < 2; ++fn)
                        acc[fm][fn] = __builtin_amdgcn_mfma_f32_16x16x32_bf16(
                            af[fm], bfr[fn], acc[fm][fn], 0, 0, 0);
                __syncthreads();
            }
#pragma unroll
            for (int fm = 0; fm < 2; ++fm)
#pragma unroll
                for (int fn = 0; fn < 2; ++fn)
#pragma unroll
                    for (int r = 0; r < 4; ++r) {
                        int row = m0 + wm * 32 + fm * 16 + quad * 4 + r;
                        int col = n0 + wn * 32 + fn * 16 + l16;
                        qkvb[(size_t)row * (3 * EE) + col] = f2bf_bits(acc[fm][fn][r] + beff[col]);
                    }
        }
    }
    grid_sync(bar_cnt, bar_gen);

    // ---------------- Phase 2: banded flash attention (4096 units, 2/wave) ------
    {
        ushortt* Pbase = (ushortt*)smem;   // per-wave slot of 16*72
        const int req = robust_req(reqp);
        const int nk_lo = -(req - 1), nk_hi = req - 1;
#pragma unroll 1
        for (int rnd = 0; rnd < 2; ++rnd) {
            int u = rnd * 2048 + w * 256 + bid;   // 0..4095
            int stile = u >> 5;
            int rem   = u & 31;
            int b = rem >> 3;
            int h = rem & 7;
            int s0 = stile * 16;

            const ushortt* qptr = qkvb + ((size_t)(s0 + l16) * BB + b) * (3 * EE) + h * HD + quad * 8;
            short8 aq = *(const short8*)qptr;

            f32x4 sc[3];
#pragma unroll
            for (int kt = 0; kt < 3; ++kt) {
                int j = s0 - 16 + kt * 16 + l16;
                int jc = min(max(j, 0), SS - 1);
                const ushortt* kp = qkvb + ((size_t)jc * BB + b) * (3 * EE) + EE + h * HD + quad * 8;
                short8 bk = *(const short8*)kp;
                sc[kt] = __builtin_amdgcn_mfma_f32_16x16x32_bf16(aq, bk, (f32x4){0.f,0.f,0.f,0.f}, 0, 0, 0);
            }

            const float scale = 0.17677669529663687f;  // 1/sqrt(32)
            float pv[3][4];
#pragma unroll
            for (int r = 0; r < 4; ++r) {
                int s = s0 + quad * 4 + r;
                float vv[3];
                float mx = -INFINITY;
#pragma unroll
                for (int kt = 0; kt < 3; ++kt) {
                    int j = s0 - 16 + kt * 16 + l16;
                    int dj = s - j;
                    bool valid = (j >= 0) && (j < SS) && (dj <= nk_hi) && (dj >= nk_lo);
                    vv[kt] = valid ? sc[kt][r] * scale : -INFINITY;
                    mx = fmaxf(mx, vv[kt]);
                }
#pragma unroll
                for (int off = 1; off <= 8; off <<= 1) mx = fmaxf(mx, __shfl_xor(mx, off));
                float sum = 0.f;
#pragma unroll
                for (int kt = 0; kt < 3; ++kt) {
                    float p = (vv[kt] > -INFINITY) ? __expf(vv[kt] - mx) : 0.f;
                    pv[kt][r] = p;
                    sum += p;
                }
#pragma unroll
                for (int off = 1; off <= 8; off <<= 1) sum += __shfl_xor(sum, off);
                float inv = 1.f / sum;
#pragma unroll
                for (int kt = 0; kt < 3; ++kt) pv[kt][r] *= inv;
            }

            ushortt* P = Pbase + w * (16 * 72);
#pragma unroll
            for (int kt = 0; kt < 3; ++kt)
#pragma unroll
                for (int r = 0; r < 4; ++r)
                    P[(quad * 4 + r) * 72 + kt * 16 + l16] = f2bf_bits(pv[kt][r]);
#pragma unroll
            for (int r = 0; r < 4; ++r)
                P[(quad * 4 + r) * 72 + 48 + l16] = 0;
            __syncthreads();

            short8 pa[2];
            pa[0] = *(const short8*)&P[l16 * 72 + quad * 8];
            pa[1] = *(const short8*)&P[l16 * 72 + 32 + quad * 8];

            f32x4 acc2[2];
            acc2[0] = (f32x4){0.f,0.f,0.f,0.f};
            acc2[1] = (f32x4){0.f,0.f,0.f,0.f};
#pragma unroll
            for (int c = 0; c < 2; ++c) {
#pragma unroll
                for (int nd = 0; nd < 2; ++nd) {
                    short8 bv;
#pragma unroll
                    for (int uu = 0; uu < 8; ++uu) {
                        int j = s0 - 16 + c * 32 + quad * 8 + uu;
                        int jc = min(max(j, 0), SS - 1);
                        bv[uu] = (short)qkvb[((size_t)jc * BB + b) * (3 * EE) + 2 * EE + h * HD + nd * 16 + l16];
                    }
                    acc2[nd] = __builtin_amdgcn_mfma_f32_16x16x32_bf16(pa[c], bv, acc2[nd], 0, 0, 0);
                }
            }
#pragma unroll
            for (int nd = 0; nd < 2; ++nd)
#pragma unroll
                for (int r = 0; r < 4; ++r) {
                    int tok = (s0 + quad * 4 + r) * BB + b;
                    ctxb[(size_t)tok * EE + h * HD + nd * 16 + l16] = f2bf_bits(acc2[nd][r]);
                }
            __syncthreads();
        }
    }
    grid_sync(bar_cnt, bar_gen);

    // ---------------- Phase 3: tail GEMM + residual + LayerNorm (BM=32) ---------
    {
        ushortt (*Alds)[40] = (ushortt (*)[40])smem;              // 32 x 40
        ushortt (*Blds)[40] = (ushortt (*)[40])(smem + 2560);     // 256 x 40
        float* part1 = (float*)(smem + 23040);                    // [4][32]
        float* part2 = (float*)(smem + 23552);                    // [4][32]
        const int wm = w >> 2, wn = w & 3;
        const int t0 = bid * 32;

        f32x4 acc[4];
#pragma unroll
        for (int fn = 0; fn < 4; ++fn) acc[fn] = (f32x4){0.f,0.f,0.f,0.f};

        for (int k0 = 0; k0 < EE; k0 += 32) {
            if (t < 128) {
                int ar = t >> 2;
                int ap = (t & 3) * 8;
                *(float4*)&Alds[ar][ap] = *(const float4*)(ctxb + (size_t)(t0 + ar) * EE + k0 + ap);
            }
#pragma unroll
            for (int i = 0; i < 2; ++i) {
                int br = (t >> 2) + i * 128;
                int bp = (t & 3) * 8;
                *(float4*)&Blds[br][bp] = *(const float4*)(W2b + (size_t)br * EE + k0 + bp);
            }
            __syncthreads();
            short8 af = *(const short8*)&Alds[wm * 16 + l16][quad * 8];
            short8 bfr[4];
#pragma unroll
            for (int fn = 0; fn < 4; ++fn)
                bfr[fn] = *(const short8*)&Blds[wn * 64 + fn * 16 + l16][quad * 8];
#pragma unroll
            for (int fn = 0; fn < 4; ++fn)
                acc[fn] = __builtin_amdgcn_mfma_f32_16x16x32_bf16(af, bfr[fn], acc[fn], 0, 0, 0);
            __syncthreads();
        }

        // epilogue: v = acc + b2 + mod; row partials
#pragma unroll
        for (int r = 0; r < 4; ++r) {
            int rowl = wm * 16 + quad * 4 + r;     // 0..31
            int row  = t0 + rowl;
            float s1 = 0.f, s2 = 0.f;
#pragma unroll
            for (int fn = 0; fn < 4; ++fn) {
                int col = wn * 64 + fn * 16 + l16;
                float v = acc[fn][r] + b2[col] + mod[(size_t)row * DD + col];
                acc[fn][r] = v;
                s1 += v;
                s2 += v * v;
            }
#pragma unroll
            for (int off = 1; off <= 8; off <<= 1) {
                s1 += __shfl_xor(s1, off);
                s2 += __shfl_xor(s2, off);
            }
            if (l16 == 0) { part1[wn * 32 + rowl] = s1; part2[wn * 32 + rowl] = s2; }
        }
        __syncthreads();
#pragma unroll
        for (int r = 0; r < 4; ++r) {
            int rowl = wm * 16 + quad * 4 + r;
            int row  = t0 + rowl;
            float S1 = part1[rowl] + part1[32 + rowl] + part1[64 + rowl] + part1[96 + rowl];
            float S2 = part2[rowl] + part2[32 + rowl] + part2[64 + rowl] + part2[96 + rowl];
            float mean = S1 * (1.f / DD);
            float var  = S2 * (1.f / DD) - mean * mean;
            float inv  = rsqrtf(var + 1e-6f);
#pragma unroll
            for (int fn = 0; fn < 4; ++fn) {
                int col = wn * 64 + fn * 16 + l16;
                out[(size_t)row * DD + col] = (acc[fn][r] - mean) * inv * gamma[col] + beta[col];
            }
        }
    }
}

extern "C" void kernel_launch(void* const* d_in, const int* in_sizes, int n_in,
                              void* d_out, int out_size, void* d_ws, size_t ws_size,
                              hipStream_t stream) {
    const float* mod  = (const float*)d_in[0];
    // d_in[1] = mask (unused)
    const float* Wq   = (const float*)d_in[2];
    const float* bq   = (const float*)d_in[3];
    const float* Wk   = (const float*)d_in[4];
    const float* bk   = (const float*)d_in[5];
    const float* Wv   = (const float*)d_in[6];
    const float* bv   = (const float*)d_in[7];
    const float* Win  = (const float*)d_in[8];
    const float* bin_ = (const float*)d_in[9];
    const float* Wout = (const float*)d_in[10];
    const float* bout = (const float*)d_in[11];
    const float* Wfc  = (const float*)d_in[12];
    const float* bfc  = (const float*)d_in[13];
    const float* gamma= (const float*)d_in[14];
    const float* beta = (const float*)d_in[15];
    const void*  reqp = d_in[16];

    float* out = (float*)d_out;

    // Workspace layout
    float*  beff = (float*)d_ws;                     // 768 f32
    float*  b2   = beff + 3 * EE;                    // 256 f32
    ushortt* Weffb = (ushortt*)(b2 + DD);            // 3E*D bf16
    ushortt* W2b   = Weffb + 3 * EE * DD;            // D*E bf16
    ushortt* qkvb  = W2b + DD * EE;                  // T*3E bf16 (12 MB)
    ushortt* ctxb  = qkvb + (size_t)TT * 3 * EE;     // T*E bf16  (4 MB)
    unsigned* bar  = (unsigned*)((char*)d_ws + (32u << 20));  // barrier counters @32MB
    unsigned* bar_cnt = bar;
    unsigned* bar_gen = bar + 1;

    hipMemsetAsync((void*)bar, 0, 256, stream);
    mega<<<NBLK, NTHR, 0, stream>>>(mod, Win, Wq, Wk, Wv, bq, bk, bv, bin_,
                                    Wfc, Wout, bout, bfc, gamma, beta, reqp,
                                    beff, b2, Weffb, W2b, qkvb, ctxb, out,
                                    bar_cnt, bar_gen);
}

// Round 8
// 129.414 us; speedup vs baseline: 2.1388x; 2.1388x over previous
//
#include <hip/hip_runtime.h>
#include <hip/hip_bf16.h>
#include <math.h>

// Problem constants (match reference)
#define SS 2048
#define BB 4
#define DD 256
#define EE 256
#define HH 8
#define HD 32
#define TT (SS*BB)   // 8192 tokens

typedef unsigned short ushortt;
typedef __attribute__((ext_vector_type(8))) short short8;
typedef __attribute__((ext_vector_type(4))) float f32x4;

__device__ __forceinline__ float bfbits2f(ushortt u) {
    return __uint_as_float(((unsigned int)u) << 16);
}
__device__ __forceinline__ ushortt f2bf_bits(float f) {
    unsigned int u = __float_as_uint(f);
    unsigned int r = u + 0x7FFFu + ((u >> 16) & 1u);  // RNE
    return (ushortt)(r >> 16);
}

__device__ __forceinline__ int robust_req(const void* p) {
    int i = *(const int*)p;
    if (i >= 1 && i <= SS) return i;
    float f = __int_as_float(i);
    if (f >= 1.f && f <= (float)SS) return (int)(f + 0.5f);
    float b = bfbits2f(*(const ushortt*)p);
    if (b >= 1.f && b <= (float)SS) return (int)(b + 0.5f);
    return 16;
}

// Weight folding + mod f32->bf16 conversion. 1024 blocks x 256 threads.
// Every block also converts a 2048-element chunk of mod (independent of fold).
__global__ __launch_bounds__(256)
void fuse_conv(const float* __restrict__ mod,
               const float* __restrict__ Win,
               const float* __restrict__ Wq, const float* __restrict__ Wk,
               const float* __restrict__ Wv,
               const float* __restrict__ bq, const float* __restrict__ bk,
               const float* __restrict__ bv, const float* __restrict__ bin_,
               const float* __restrict__ Wfc, const float* __restrict__ Wout,
               const float* __restrict__ bout, const float* __restrict__ bfc,
               ushortt* __restrict__ Weffb, float* __restrict__ beff,
               ushortt* __restrict__ W2b, float* __restrict__ b2,
               ushortt* __restrict__ modb) {
    __shared__ float red[4];
    const int t = threadIdx.x;

    // ---- mod conversion chunk (issued first; loads pipeline under the fold) ----
    {
        size_t base = (size_t)blockIdx.x * 2048 + (size_t)t * 8;
        float4 v0 = *(const float4*)(mod + base);
        float4 v1 = *(const float4*)(mod + base + 4);
        ushort4 o0, o1;
        o0.x = f2bf_bits(v0.x); o0.y = f2bf_bits(v0.y);
        o0.z = f2bf_bits(v0.z); o0.w = f2bf_bits(v0.w);
        o1.x = f2bf_bits(v1.x); o1.y = f2bf_bits(v1.y);
        o1.z = f2bf_bits(v1.z); o1.w = f2bf_bits(v1.w);
        *(ushort4*)(modb + base)     = o0;
        *(ushort4*)(modb + base + 4) = o1;
    }

    // ---- weight fold ----
    float tb;
    if (blockIdx.x < 3 * EE) {
        int r = blockIdx.x;
        int i = r / EE;
        const float* Wi = (i == 0) ? Wq : ((i == 1) ? Wk : Wv);
        const float* bi = (i == 0) ? bq : ((i == 1) ? bk : bv);
        float acc = 0.f;
        for (int e1 = 0; e1 < EE; ++e1) acc += Win[r * EE + e1] * Wi[e1 * DD + t];
        Weffb[(size_t)r * DD + t] = f2bf_bits(acc);
        tb = Win[r * EE + t] * bi[t];
    } else {
        int d = blockIdx.x - 3 * EE;
        float acc = 0.f;
        for (int e = 0; e < EE; ++e) acc += Wfc[d * EE + e] * Wout[e * EE + t];
        W2b[(size_t)d * EE + t] = f2bf_bits(acc);
        tb = Wfc[d * EE + t] * bout[t];
    }
#pragma unroll
    for (int off = 32; off >= 1; off >>= 1) tb += __shfl_xor(tb, off);
    if ((t & 63) == 0) red[t >> 6] = tb;
    __syncthreads();
    if (t == 0) {
        float s = red[0] + red[1] + red[2] + red[3];
        if (blockIdx.x < 3 * EE) beff[blockIdx.x] = s + bin_[blockIdx.x];
        else                     b2[blockIdx.x - 3 * EE] = s + bfc[blockIdx.x - 3 * EE];
    }
}

// qkv GEMM (MFMA, TN): qkv[m][n] = sum_k modb[m][k]*Weffb[n][k] + beff[n] -> bf16
// BM=64, BN=192, BK=64. Grid (4, 128) = 512 blocks, 256 thr = 4 waves (n-split 48 each).
__global__ __launch_bounds__(256)
void gemm_qkv(const ushortt* __restrict__ A, const ushortt* __restrict__ Bw,
              const float* __restrict__ bias, ushortt* __restrict__ C) {
    __shared__ __align__(16) ushortt Alds[64][72];    // BK=64 + 8 pad
    __shared__ __align__(16) ushortt Blds[192][72];
    const int t    = threadIdx.x;
    const int lane = t & 63;
    const int w    = t >> 6;          // wave 0..3, covers cols [w*48, w*48+48)
    const int quad = lane >> 4;
    const int l16  = lane & 15;
    const int n0   = blockIdx.x * 192;
    const int m0   = blockIdx.y * 64;
    const int N    = 3 * EE, K = DD;

    f32x4 acc[4][3];
#pragma unroll
    for (int fm = 0; fm < 4; ++fm)
#pragma unroll
        for (int fn = 0; fn < 3; ++fn) acc[fm][fn] = (f32x4){0.f,0.f,0.f,0.f};

    for (int k0 = 0; k0 < K; k0 += 64) {
        // stage A: 64x64 (2 x 16B per thread)
        {
            int row = t >> 2, c8 = (t & 3) * 8;
            const ushortt* ap = A + (size_t)(m0 + row) * K + k0;
            *(float4*)&Alds[row][c8]      = *(const float4*)(ap + c8);
            *(float4*)&Alds[row][c8 + 32] = *(const float4*)(ap + c8 + 32);
        }
        // stage B: 192x64 (6 x 16B per thread)
#pragma unroll
        for (int i = 0; i < 6; ++i) {
            int slot = t + 256 * i;           // 0..1535
            int row = slot >> 3, c8 = (slot & 7) * 8;
            *(float4*)&Blds[row][c8] = *(const float4*)(Bw + (size_t)(n0 + row) * K + k0 + c8);
        }
        __syncthreads();
        short8 af[4][2], bfr[3][2];
#pragma unroll
        for (int fm = 0; fm < 4; ++fm)
#pragma unroll
            for (int kf = 0; kf < 2; ++kf)
                af[fm][kf] = *(const short8*)&Alds[fm * 16 + l16][kf * 32 + quad * 8];
#pragma unroll
        for (int fn = 0; fn < 3; ++fn)
#pragma unroll
            for (int kf = 0; kf < 2; ++kf)
                bfr[fn][kf] = *(const short8*)&Blds[w * 48 + fn * 16 + l16][kf * 32 + quad * 8];
#pragma unroll
        for (int kf = 0; kf < 2; ++kf)
#pragma unroll
            for (int fm = 0; fm < 4; ++fm)
#pragma unroll
                for (int fn = 0; fn < 3; ++fn)
                    acc[fm][fn] = __builtin_amdgcn_mfma_f32_16x16x32_bf16(
                        af[fm][kf], bfr[fn][kf], acc[fm][fn], 0, 0, 0);
        __syncthreads();
    }
#pragma unroll
    for (int fm = 0; fm < 4; ++fm)
#pragma unroll
        for (int fn = 0; fn < 3; ++fn)
#pragma unroll
            for (int r = 0; r < 4; ++r) {
                int row = m0 + fm * 16 + quad * 4 + r;
                int col = n0 + w * 48 + fn * 16 + l16;
                C[(size_t)row * N + col] = f2bf_bits(acc[fm][fn][r] + bias[col]);
            }
}

// MFMA banded flash attention (verbatim from R6 — passing). 1024 blocks x 256.
__global__ __launch_bounds__(256)
void attn_mfma(const ushortt* __restrict__ qkv,
               const void* __restrict__ reqp,
               ushortt* __restrict__ ctx) {
    __shared__ __align__(16) ushortt Plds[4][16 * 72];
    const int t    = threadIdx.x;
    const int w    = t >> 6;
    const int lane = t & 63;
    const int l16  = lane & 15;
    const int quad = lane >> 4;
    const int wid  = blockIdx.x * 4 + w;    // 0..4095
    const int stile = wid >> 5;
    const int rem   = wid & 31;
    const int b = rem >> 3;
    const int h = rem & 7;
    const int s0 = stile * 16;
    const int req = robust_req(reqp);

    const ushortt* qptr = qkv + ((size_t)(s0 + l16) * BB + b) * (3 * EE) + h * HD + quad * 8;
    short8 aq = *(const short8*)qptr;

    f32x4 sc[3];
#pragma unroll
    for (int kt = 0; kt < 3; ++kt) {
        int j = s0 - 16 + kt * 16 + l16;
        int jc = min(max(j, 0), SS - 1);
        const ushortt* kp = qkv + ((size_t)jc * BB + b) * (3 * EE) + EE + h * HD + quad * 8;
        short8 bk = *(const short8*)kp;
        sc[kt] = __builtin_amdgcn_mfma_f32_16x16x32_bf16(aq, bk, (f32x4){0.f,0.f,0.f,0.f}, 0, 0, 0);
    }

    const float scale = 0.17677669529663687f;  // 1/sqrt(32)
    float pv[3][4];
#pragma unroll
    for (int r = 0; r < 4; ++r) {
        int s = s0 + quad * 4 + r;
        float vv[3];
        float mx = -INFINITY;
#pragma unroll
        for (int kt = 0; kt < 3; ++kt) {
            int j = s0 - 16 + kt * 16 + l16;
            int dj = s - j;
            bool valid = (j >= 0) && (j < SS) && (dj < req) && (-dj < req);
            vv[kt] = valid ? sc[kt][r] * scale : -INFINITY;
            mx = fmaxf(mx, vv[kt]);
        }
#pragma unroll
        for (int off = 1; off <= 8; off <<= 1) mx = fmaxf(mx, __shfl_xor(mx, off));
        float sum = 0.f;
#pragma unroll
        for (int kt = 0; kt < 3; ++kt) {
            float p = (vv[kt] > -INFINITY) ? __expf(vv[kt] - mx) : 0.f;
            pv[kt][r] = p;
            sum += p;
        }
#pragma unroll
        for (int off = 1; off <= 8; off <<= 1) sum += __shfl_xor(sum, off);
        float inv = 1.f / sum;
#pragma unroll
        for (int kt = 0; kt < 3; ++kt) pv[kt][r] *= inv;
    }

    ushortt* P = &Plds[w][0];
#pragma unroll
    for (int kt = 0; kt < 3; ++kt)
#pragma unroll
        for (int r = 0; r < 4; ++r)
            P[(quad * 4 + r) * 72 + kt * 16 + l16] = f2bf_bits(pv[kt][r]);
#pragma unroll
    for (int r = 0; r < 4; ++r)
        P[(quad * 4 + r) * 72 + 48 + l16] = 0;
    __syncthreads();

    short8 pa[2];
    pa[0] = *(const short8*)&P[l16 * 72 + quad * 8];
    pa[1] = *(const short8*)&P[l16 * 72 + 32 + quad * 8];

    f32x4 acc[2];
    acc[0] = (f32x4){0.f,0.f,0.f,0.f};
    acc[1] = (f32x4){0.f,0.f,0.f,0.f};
#pragma unroll
    for (int c = 0; c < 2; ++c) {
#pragma unroll
        for (int nd = 0; nd < 2; ++nd) {
            short8 bv;
#pragma unroll
            for (int u = 0; u < 8; ++u) {
                int j = s0 - 16 + c * 32 + quad * 8 + u;
                int jc = min(max(j, 0), SS - 1);
                bv[u] = (short)qkv[((size_t)jc * BB + b) * (3 * EE) + 2 * EE + h * HD + nd * 16 + l16];
            }
            acc[nd] = __builtin_amdgcn_mfma_f32_16x16x32_bf16(pa[c], bv, acc[nd], 0, 0, 0);
        }
    }

#pragma unroll
    for (int nd = 0; nd < 2; ++nd)
#pragma unroll
        for (int r = 0; r < 4; ++r) {
            int tok = (s0 + quad * 4 + r) * BB + b;
            ctx[(size_t)tok * EE + h * HD + nd * 16 + l16] = f2bf_bits(acc[nd][r]);
        }
}

// Tail GEMM + residual + LayerNorm. BM=32, BN=256 (full row), BK=64.
// Grid 256 blocks, 256 thr = 4 waves (n-split 64 each).
__global__ __launch_bounds__(256)
void gemm_tail_ln(const ushortt* __restrict__ A, const ushortt* __restrict__ Bw,
                  const float* __restrict__ b2, const float* __restrict__ mod,
                  const float* __restrict__ gamma, const float* __restrict__ beta,
                  float* __restrict__ out) {
    __shared__ __align__(16) ushortt Alds[32][72];
    __shared__ __align__(16) ushortt Blds[256][72];
    __shared__ float part1[4][32], part2[4][32];
    const int t    = threadIdx.x;
    const int lane = t & 63;
    const int w    = t >> 6;          // col group 0..3
    const int quad = lane >> 4;
    const int l16  = lane & 15;
    const int m0   = blockIdx.x * 32;
    const int K    = EE;

    f32x4 acc[2][4];
#pragma unroll
    for (int fm = 0; fm < 2; ++fm)
#pragma unroll
        for (int fn = 0; fn < 4; ++fn) acc[fm][fn] = (f32x4){0.f,0.f,0.f,0.f};

    for (int k0 = 0; k0 < K; k0 += 64) {
        // stage A: 32x64 (1 x 16B per thread)
        {
            int row = t >> 3, c8 = (t & 7) * 8;
            *(float4*)&Alds[row][c8] = *(const float4*)(A + (size_t)(m0 + row) * K + k0 + c8);
        }
        // stage B: 256x64 (8 x 16B per thread)
#pragma unroll
        for (int i = 0; i < 8; ++i) {
            int slot = t + 256 * i;           // 0..2047
            int row = slot >> 3, c8 = (slot & 7) * 8;
            *(float4*)&Blds[row][c8] = *(const float4*)(Bw + (size_t)row * K + k0 + c8);
        }
        __syncthreads();
        short8 af[2][2], bfr[4][2];
#pragma unroll
        for (int fm = 0; fm < 2; ++fm)
#pragma unroll
            for (int kf = 0; kf < 2; ++kf)
                af[fm][kf] = *(const short8*)&Alds[fm * 16 + l16][kf * 32 + quad * 8];
#pragma unroll
        for (int fn = 0; fn < 4; ++fn)
#pragma unroll
            for (int kf = 0; kf < 2; ++kf)
                bfr[fn][kf] = *(const short8*)&Blds[w * 64 + fn * 16 + l16][kf * 32 + quad * 8];
#pragma unroll
        for (int kf = 0; kf < 2; ++kf)
#pragma unroll
            for (int fm = 0; fm < 2; ++fm)
#pragma unroll
                for (int fn = 0; fn < 4; ++fn)
                    acc[fm][fn] = __builtin_amdgcn_mfma_f32_16x16x32_bf16(
                        af[fm][kf], bfr[fn][kf], acc[fm][fn], 0, 0, 0);
        __syncthreads();
    }

    // epilogue: v = acc + b2 + mod; row partials -> LDS -> LN -> out
#pragma unroll
    for (int fm = 0; fm < 2; ++fm) {
#pragma unroll
        for (int r = 0; r < 4; ++r) {
            int rowl = fm * 16 + quad * 4 + r;     // 0..31
            int row  = m0 + rowl;
            float s1 = 0.f, s2 = 0.f;
#pragma unroll
            for (int fn = 0; fn < 4; ++fn) {
                int col = w * 64 + fn * 16 + l16;
                float v = acc[fm][fn][r] + b2[col] + mod[(size_t)row * DD + col];
                acc[fm][fn][r] = v;
                s1 += v;
                s2 += v * v;
            }
#pragma unroll
            for (int off = 1; off <= 8; off <<= 1) {
                s1 += __shfl_xor(s1, off);
                s2 += __shfl_xor(s2, off);
            }
            if (l16 == 0) { part1[w][rowl] = s1; part2[w][rowl] = s2; }
        }
    }
    __syncthreads();
#pragma unroll
    for (int fm = 0; fm < 2; ++fm) {
#pragma unroll
        for (int r = 0; r < 4; ++r) {
            int rowl = fm * 16 + quad * 4 + r;
            int row  = m0 + rowl;
            float S1 = part1[0][rowl] + part1[1][rowl] + part1[2][rowl] + part1[3][rowl];
            float S2 = part2[0][rowl] + part2[1][rowl] + part2[2][rowl] + part2[3][rowl];
            float mean = S1 * (1.f / DD);
            float var  = S2 * (1.f / DD) - mean * mean;
            float inv  = rsqrtf(var + 1e-6f);
#pragma unroll
            for (int fn = 0; fn < 4; ++fn) {
                int col = w * 64 + fn * 16 + l16;
                out[(size_t)row * DD + col] = (acc[fm][fn][r] - mean) * inv * gamma[col] + beta[col];
            }
        }
    }
}

extern "C" void kernel_launch(void* const* d_in, const int* in_sizes, int n_in,
                              void* d_out, int out_size, void* d_ws, size_t ws_size,
                              hipStream_t stream) {
    const float* mod  = (const float*)d_in[0];
    // d_in[1] = mask (unused)
    const float* Wq   = (const float*)d_in[2];
    const float* bq   = (const float*)d_in[3];
    const float* Wk   = (const float*)d_in[4];
    const float* bk   = (const float*)d_in[5];
    const float* Wv   = (const float*)d_in[6];
    const float* bv   = (const float*)d_in[7];
    const float* Win  = (const float*)d_in[8];
    const float* bin_ = (const float*)d_in[9];
    const float* Wout = (const float*)d_in[10];
    const float* bout = (const float*)d_in[11];
    const float* Wfc  = (const float*)d_in[12];
    const float* bfc  = (const float*)d_in[13];
    const float* gamma= (const float*)d_in[14];
    const float* beta = (const float*)d_in[15];
    const void*  reqp = d_in[16];

    float* out = (float*)d_out;

    // Workspace layout
    float*  beff = (float*)d_ws;                     // 768 f32
    float*  b2   = beff + 3 * EE;                    // 256 f32
    ushortt* Weffb = (ushortt*)(b2 + DD);            // 3E*D bf16
    ushortt* W2b   = Weffb + 3 * EE * DD;            // D*E bf16
    ushortt* modb  = W2b + DD * EE;                  // T*D bf16  (4 MB)
    ushortt* qkvb  = modb + (size_t)TT * DD;         // T*3E bf16 (12 MB)
    ushortt* ctxb  = qkvb + (size_t)TT * 3 * EE;     // T*E bf16  (4 MB)

    // 1) fold weights + biases, convert mod -> bf16
    fuse_conv<<<1024, 256, 0, stream>>>(mod, Win, Wq, Wk, Wv, bq, bk, bv, bin_,
                                        Wfc, Wout, bout, bfc,
                                        Weffb, beff, W2b, b2, modb);
    // 2) qkv GEMM (MFMA): [T][3E] = modb x Weffb^T + beff -> bf16
    gemm_qkv<<<dim3(4, TT / 64), 256, 0, stream>>>(modb, Weffb, beff, qkvb);
    // 3) banded flash attention (MFMA) -> bf16 ctx
    attn_mfma<<<4096 / 4, 256, 0, stream>>>(qkvb, reqp, ctxb);
    // 4) tail GEMM + residual + LayerNorm -> f32 d_out
    gemm_tail_ln<<<TT / 32, 256, 0, stream>>>(ctxb, W2b, b2, mod, gamma, beta, out);
}